// Round 7
// baseline (719.722 us; speedup 1.0000x reference)
//
#include <hip/hip_runtime.h>
#include <cstdint>

// ---------------------------------------------------------------------------
// GCN 2-layer forward, fp32, MI355X.
// out = Â ( drop( Â (x W1) + b1 ) ) W2 + b2,  Â = D^-1/2 (A+I) D^-1/2
//
// Round-7 = round-5 source resubmitted verbatim (rounds 5 and 6 both hit
// GPU-broker acquisition timeouts; this source has never been measured).
//
// Structure:
//  - adjacency = per-target linked list (atomicExch head + coalesced 8B
//    packed[e] = {src,next}); degree via chain walk.
//  - k_mm1 LDS-tiled (128 rows x K-tile 64, x transposed in LDS, W1 in LDS)
//    -> coalesced global x reads instead of 64-line-divergent float4 gather.
//  - gather1 fused with bias+dropout+rescale (threefry hides under chain
//    latency); gather2 fused with the 16->40 GEMV epilogue (LDS agg tile).
//  - y1 lives in d_out (dead before the fused mm2 overwrites d_out);
//    y2 lives in ws. ws footprint identical to the proven round-4 layout.
//
// Dropout mask = partitionable threefry2x32 (verified round 2):
//   bits[i] = o0^o1 of tf2x32(key=(0,42), (0,i)); keep <=> bits < 2^31.
// ---------------------------------------------------------------------------

#define TFR(R) { x0 += x1; x1 = (x1 << (R)) | (x1 >> (32 - (R))); x1 ^= x0; }

__device__ __forceinline__ void tf2x32(uint32_t k0, uint32_t k1,
                                       uint32_t c0, uint32_t c1,
                                       uint32_t& o0, uint32_t& o1) {
    const uint32_t kx = k0 ^ k1 ^ 0x1BD11BDAu;
    uint32_t x0 = c0 + k0, x1 = c1 + k1;
    TFR(13) TFR(15) TFR(26) TFR(6)   x0 += k1; x1 += kx + 1u;
    TFR(17) TFR(29) TFR(16) TFR(24)  x0 += kx; x1 += k0 + 2u;
    TFR(13) TFR(15) TFR(26) TFR(6)   x0 += k0; x1 += k1 + 3u;
    TFR(17) TFR(29) TFR(16) TFR(24)  x0 += k1; x1 += kx + 4u;
    TFR(13) TFR(15) TFR(26) TFR(6)   x0 += kx; x1 += k0 + 5u;
    o0 = x0; o1 = x1;
}

#define NIL 0xFFFFFFFFu

// head = NIL; thread 0 runs threefry KAT
__global__ void k_init(uint32_t* __restrict__ head, int N, uint32_t* __restrict__ kat) {
    int i = blockIdx.x * blockDim.x + threadIdx.x;
    if (i < N) head[i] = NIL;
    if (i == 0) {
        uint32_t o0, o1;
        tf2x32(0u, 0u, 0u, 0u, o0, o1);
        *kat = (o0 == 0x6b200159u && o1 == 0x99ba4efeu) ? 1u : 0u;
    }
}

// linked-list build: coalesced 8B writes + 1 atomicExch per edge
__global__ void k_build(const int* __restrict__ row, const int* __restrict__ col,
                        uint32_t* __restrict__ head, uint2* __restrict__ packed, int E) {
    int e = blockIdx.x * blockDim.x + threadIdx.x;
    if (e >= E) return;
    uint32_t r = (uint32_t)row[e];
    int c = col[e];
    uint32_t old = atomicExch(&head[c], (uint32_t)e);
    packed[e] = make_uint2(r, old);
}

// chain walk -> in-degree -> dinv = rsqrt(1 + deg)
__global__ void k_walk(const uint32_t* __restrict__ head, const uint2* __restrict__ packed,
                       float* __restrict__ dinv, int N) {
    int n = blockIdx.x * blockDim.x + threadIdx.x;
    if (n >= N) return;
    uint32_t e = head[n];
    int cnt = 0;
    while (e != NIL) { cnt++; e = packed[e].y; }
    dinv[n] = rsqrtf(1.0f + (float)cnt);
}

// y1 = dinv * (x @ W1)   ([N,512]@[512,16]) — LDS-tiled, coalesced x reads.
// Block: 256 thr, 128 rows, K-tile 64. Xs transposed [k][row] (stride 129).
// Thread: rows {rq, rq+64} (rq = lane), feats {4fq..4fq+3} (fq = wave id).
__global__ __launch_bounds__(256) void k_mm1(
    const float* __restrict__ x, const float* __restrict__ W1,
    const float* __restrict__ dinv, float* __restrict__ y1, int N) {
    __shared__ float Ws[512 * 16];   // 32 KB, layout [k][16]
    __shared__ float Xs[64 * 129];   // 33 KB, layout [k][row], pad stride 129
    const int tid = threadIdx.x;
    const int row0 = blockIdx.x * 128;

    {   // stage W1 (exactly 2048 float4)
        const float4* w4 = reinterpret_cast<const float4*>(W1);
        float4* s4 = reinterpret_cast<float4*>(Ws);
#pragma unroll
        for (int i = 0; i < 8; ++i) s4[tid + i * 256] = w4[tid + i * 256];
    }

    const int rq = tid & 63;   // lane
    const int fq = tid >> 6;   // wave id 0..3 (wave-uniform)
    float acc0[4] = {0.f, 0.f, 0.f, 0.f};
    float acc1[4] = {0.f, 0.f, 0.f, 0.f};

    for (int kt = 0; kt < 8; ++kt) {
        __syncthreads();  // Xs safe to overwrite
#pragma unroll
        for (int i = 0; i < 8; ++i) {
            int idx = tid + i * 256;        // 0..2047
            int r = idx >> 4;               // 0..127
            int c4 = idx & 15;              // float4 within 64-col tile
            int grow = row0 + r;
            float4 v = make_float4(0.f, 0.f, 0.f, 0.f);
            if (grow < N)
                v = *reinterpret_cast<const float4*>(x + (size_t)grow * 512 + kt * 64 + c4 * 4);
            int kb = 4 * c4;
            Xs[(kb + 0) * 129 + r] = v.x;
            Xs[(kb + 1) * 129 + r] = v.y;
            Xs[(kb + 2) * 129 + r] = v.z;
            Xs[(kb + 3) * 129 + r] = v.w;
        }
        __syncthreads();
        const float4* wv4 = reinterpret_cast<const float4*>(Ws) + (size_t)kt * 64 * 4 + fq;
#pragma unroll 4
        for (int k = 0; k < 64; ++k) {
            float xv0 = Xs[k * 129 + rq];
            float xv1 = Xs[k * 129 + rq + 64];
            float4 wv = wv4[k * 4];
            acc0[0] += xv0 * wv.x; acc0[1] += xv0 * wv.y;
            acc0[2] += xv0 * wv.z; acc0[3] += xv0 * wv.w;
            acc1[0] += xv1 * wv.x; acc1[1] += xv1 * wv.y;
            acc1[2] += xv1 * wv.z; acc1[3] += xv1 * wv.w;
        }
    }
    int r0 = row0 + rq, r1 = r0 + 64;
    if (r0 < N) {
        float dv = dinv[r0];
        float4 o = make_float4(dv * acc0[0], dv * acc0[1], dv * acc0[2], dv * acc0[3]);
        *reinterpret_cast<float4*>(y1 + (size_t)r0 * 16 + fq * 4) = o;
    }
    if (r1 < N) {
        float dv = dinv[r1];
        float4 o = make_float4(dv * acc1[0], dv * acc1[1], dv * acc1[2], dv * acc1[3]);
        *reinterpret_cast<float4*>(y1 + (size_t)r1 * 16 + fq * 4) = o;
    }
}

// gather1 + bias + dropout + rescale:
// y2[c,:] = dinv[c] * mask * 2 * ( dinv[c]*(y1[c,:] + sum y1[src,:]) + b1 )
// 4 lanes per node; lane j owns feats 4j..4j+3.
__global__ __launch_bounds__(256) void k_gather_fin(
    const uint32_t* __restrict__ head, const uint2* __restrict__ packed,
    const float* __restrict__ dinv, const float* __restrict__ b1,
    const float* __restrict__ y1, float* __restrict__ y2, int N,
    const uint32_t* __restrict__ kat) {
    int t = blockIdx.x * 256 + threadIdx.x;
    int c = t >> 2;
    int j = t & 3;
    if (c >= N) return;
    float4 acc = *reinterpret_cast<const float4*>(y1 + (size_t)c * 16 + j * 4);  // self
    uint32_t e = head[c];
    while (e != NIL) {
        uint2 p = packed[e];
        const float4 v = *reinterpret_cast<const float4*>(y1 + (size_t)p.x * 16 + j * 4);
        acc.x += v.x; acc.y += v.y; acc.z += v.z; acc.w += v.w;
        e = p.y;
    }
    float dc = dinv[c];
    float4 bv = *reinterpret_cast<const float4*>(b1 + 4 * j);
    float ag[4] = {dc * acc.x + bv.x, dc * acc.y + bv.y,
                   dc * acc.z + bv.z, dc * acc.w + bv.w};
    uint32_t ok = *kat;
    float o[4];
#pragma unroll
    for (int ii = 0; ii < 4; ++ii) {
        uint32_t idx = (uint32_t)c * 16u + (uint32_t)(4 * j + ii);
        uint32_t o0, o1;
        tf2x32(0u, 42u, 0u, idx, o0, o1);
        uint32_t bits = o0 ^ o1;
        float hv = (bits & 0x80000000u) ? 0.0f : ag[ii] * 2.0f;
        if (ok == 0u) hv = 0.0f;  // KAT-fail signature
        o[ii] = dc * hv;
    }
    *reinterpret_cast<float4*>(y2 + (size_t)c * 16 + 4 * j) =
        make_float4(o[0], o[1], o[2], o[3]);
}

// gather2 + GEMV: out[c,:] = ( dinv[c]*(y2[c,:] + sum y2[src,:]) ) @ W2 + b2
// Phase 1: 4 lanes/node gather -> LDS agg tile (stride 17, conflict-free).
// Phase 2 (post-barrier): same 4 lanes compute 10 outputs each.
__global__ __launch_bounds__(256) void k_gather_mm2(
    const uint32_t* __restrict__ head, const uint2* __restrict__ packed,
    const float* __restrict__ dinv, const float* __restrict__ y2,
    const float* __restrict__ W2, const float* __restrict__ b2,
    float* __restrict__ out, int N) {
    __shared__ float W2s[16 * 40];
    __shared__ float b2s[40];
    __shared__ float aggS[64 * 17];
    const int tid = threadIdx.x;
    for (int i = tid; i < 640; i += 256) W2s[i] = W2[i];
    if (tid < 40) b2s[tid] = b2[tid];
    const int cl = tid >> 2;           // node within block, 0..63
    const int j = tid & 3;
    const int c = blockIdx.x * 64 + cl;
    if (c < N) {
        float4 acc = *reinterpret_cast<const float4*>(y2 + (size_t)c * 16 + j * 4);
        uint32_t e = head[c];
        while (e != NIL) {
            uint2 p = packed[e];
            const float4 v = *reinterpret_cast<const float4*>(y2 + (size_t)p.x * 16 + j * 4);
            acc.x += v.x; acc.y += v.y; acc.z += v.z; acc.w += v.w;
            e = p.y;
        }
        float dc = dinv[c];
        aggS[cl * 17 + 4 * j + 0] = dc * acc.x;
        aggS[cl * 17 + 4 * j + 1] = dc * acc.y;
        aggS[cl * 17 + 4 * j + 2] = dc * acc.z;
        aggS[cl * 17 + 4 * j + 3] = dc * acc.w;
    }
    __syncthreads();
    if (c < N) {
        float a[16];
#pragma unroll
        for (int k = 0; k < 16; ++k) a[k] = aggS[cl * 17 + k];
        float o[10];
#pragma unroll
        for (int m = 0; m < 10; ++m) o[m] = b2s[j * 10 + m];
#pragma unroll
        for (int k = 0; k < 16; ++k) {
            float av = a[k];
#pragma unroll
            for (int m = 0; m < 10; ++m) o[m] += av * W2s[k * 40 + j * 10 + m];
        }
        float* op = out + (size_t)c * 40 + j * 10;
#pragma unroll
        for (int m = 0; m < 10; ++m) op[m] = o[m];
    }
}

extern "C" void kernel_launch(void* const* d_in, const int* in_sizes, int n_in,
                              void* d_out, int out_size, void* d_ws, size_t ws_size,
                              hipStream_t stream) {
    const float* x  = (const float*)d_in[0];
    const int*   ei = (const int*)d_in[1];
    const float* W1 = (const float*)d_in[2];
    const float* b1 = (const float*)d_in[3];
    const float* W2 = (const float*)d_in[4];
    const float* b2 = (const float*)d_in[5];
    float* out = (float*)d_out;

    const int E = in_sizes[1] / 2;
    const int N = in_sizes[0] / 512;
    const int* row = ei;       // sources
    const int* col = ei + E;   // targets

    // ws (≈33 MB, same footprint as proven round-4 layout):
    // head[N] | dinv[N] | packed[E] uint2 | y2[16N] | kat
    uint32_t* head = (uint32_t*)d_ws;
    float*    dinv = (float*)(head + N);
    uint2*    packed = (uint2*)(dinv + N);          // 8B aligned (2N words)
    float*    y2   = (float*)(packed + E);          // 16B aligned
    uint32_t* kat  = (uint32_t*)(y2 + (size_t)16 * N);

    // d_out doubles as y1 (16N floats), dead before k_gather_mm2 writes out.
    float* y1 = (float*)d_out;

    dim3 blk(256);
    dim3 gN((N + 255) / 256);
    dim3 gE((E + 255) / 256);
    dim3 gMM((N + 127) / 128);
    dim3 gN4((N * 4 + 255) / 256);

    k_init<<<gN, blk, 0, stream>>>(head, N, kat);
    k_build<<<gE, blk, 0, stream>>>(row, col, head, packed, E);
    k_walk<<<gN, blk, 0, stream>>>(head, packed, dinv, N);
    k_mm1<<<gMM, blk, 0, stream>>>(x, W1, dinv, y1, N);
    k_gather_fin<<<gN4, blk, 0, stream>>>(head, packed, dinv, b1, y1, y2, N, kat);
    k_gather_mm2<<<gN4, blk, 0, stream>>>(head, packed, dinv, y2, W2, b2, out, N);
}